// Round 3
// baseline (78.663 us; speedup 1.0000x reference)
//
#include <hip/hip_runtime.h>

// Npool: soft max-pool along last axis.
// x: (8,32,64,4096) f32 -> out: (8,32,64,2047) f32, window=4, stride=2, nn=1.
// Per window: mi = first-argmax. mi in {0,3} -> out = max (eff=0).
//             mi in {1,2} -> out = 0.25*win[mi-1] + 0.5*win[mi] + 0.25*win[mi+1].
//
// Flat-output decomposition: each thread computes NCHUNK groups of 4 ADJACENT
// outputs. 4 adjacent windows share float2s: 5 x float2 loads -> 4 outputs
// (10 B/out vs 16), stored as one aligned float4 (flat 4g*4B is 16B-aligned,
// sidestepping the misaligned 8188-byte output row pitch). Row straddle
// (o0 > 2043, ~1/512 of groups) takes a rare per-element recompute path;
// the speculative fast-path loads are always in-bounds.

#define OUT_W 2047u
#define ROW_W 4096
#define NCHUNK 4

__device__ __forceinline__ float pool4(float w0, float w1, float w2, float w3) {
    int mi = 0; float m = w0;
    if (w1 > m) { m = w1; mi = 1; }
    if (w2 > m) { m = w2; mi = 2; }
    if (w3 > m) { m = w3; mi = 3; }
    const float lo = (mi == 1) ? w0 : w1;
    const float hi = (mi == 1) ? w2 : w3;
    const float interior = 0.25f * lo + 0.5f * m + 0.25f * hi;
    return (mi == 0 || mi == 3) ? m : interior;
}

__global__ __launch_bounds__(256) void npool_kernel(const float* __restrict__ x,
                                                    float* __restrict__ out,
                                                    unsigned ngpc) {  // groups per chunk
    const unsigned t = blockIdx.x * 256 + threadIdx.x;

    unsigned fo[NCHUNK], o0[NCHUNK];
    float2 c[NCHUNK][5];

    // Phase 1: all address math + all 20 loads issued up front (MLP).
    #pragma unroll
    for (int k = 0; k < NCHUNK; ++k) {
        const unsigned g = t + (unsigned)k * ngpc;
        fo[k] = 4u * g;
        const unsigned row = fo[k] / OUT_W;          // magic-mul division
        o0[k] = fo[k] - row * OUT_W;
        const float* p = x + (size_t)row * ROW_W + 2u * o0[k];
        #pragma unroll
        for (int j = 0; j < 5; ++j)
            c[k][j] = *reinterpret_cast<const float2*>(p + 2 * j);
    }

    // Phase 2: compute + vectorized stores.
    #pragma unroll
    for (int k = 0; k < NCHUNK; ++k) {
        float4 r;
        r.x = pool4(c[k][0].x, c[k][0].y, c[k][1].x, c[k][1].y);
        r.y = pool4(c[k][1].x, c[k][1].y, c[k][2].x, c[k][2].y);
        r.z = pool4(c[k][2].x, c[k][2].y, c[k][3].x, c[k][3].y);
        r.w = pool4(c[k][3].x, c[k][3].y, c[k][4].x, c[k][4].y);

        if (o0[k] > OUT_W - 4u) {                    // row straddle: rare
            float rr[4];
            #pragma unroll
            for (int i = 0; i < 4; ++i) {
                const unsigned fi = fo[k] + (unsigned)i;
                const unsigned ri = fi / OUT_W;
                const unsigned oi = fi - ri * OUT_W;
                const float* q = x + (size_t)ri * ROW_W + 2u * oi;
                const float2 d0 = *reinterpret_cast<const float2*>(q);
                const float2 d1 = *reinterpret_cast<const float2*>(q + 2);
                rr[i] = pool4(d0.x, d0.y, d1.x, d1.y);
            }
            r = make_float4(rr[0], rr[1], rr[2], rr[3]);
        }

        *reinterpret_cast<float4*>(out + fo[k]) = r;
    }
}

extern "C" void kernel_launch(void* const* d_in, const int* in_sizes, int n_in,
                              void* d_out, int out_size, void* d_ws, size_t ws_size,
                              hipStream_t stream) {
    const float* x = (const float*)d_in[0];
    float* out = (float*)d_out;

    const unsigned rows = (unsigned)(in_sizes[0] / ROW_W);     // 16384
    const unsigned total_out = rows * OUT_W;                   // 33,538,048
    const unsigned groups = total_out / 4u;                    // 8,384,512
    const unsigned ngpc = groups / NCHUNK;                     // 2,096,128
    const unsigned blocks = ngpc / 256u;                       // 8188 (exact)
    npool_kernel<<<blocks, 256, 0, stream>>>(x, out, ngpc);
}

// Round 4
// 74.651 us; speedup vs baseline: 1.0537x; 1.0537x over previous
//
#include <hip/hip_runtime.h>

// Npool: soft max-pool along last axis.
// x: (8,32,64,4096) f32 -> out: (8,32,64,2047) f32, window=4, stride=2, nn=1.
// Per window: mi = first-argmax. mi in {0,3} -> out = max (eff=0).
//             mi in {1,2} -> out = 0.25*win[mi-1] + 0.5*win[mi] + 0.25*win[mi+1].
//
// Structure: block = one row. 4 waves x 4 segments of 128 outputs.
// Lane i loads ONE float4 x[4i..4i+3] per segment: 16B lane-stride, fully
// dense (copy-bench pattern), exactly-compulsory 8B/output load traffic.
// Window o=2i comes from the float4 itself; o=2i+1 needs next lane's .x,.y
// -> 2x __shfl_down(1). Lane 63 gets its neighbor pair via a tiny masked
// float2 load. Stores: two scalar dwords (float2 would be 8B-misaligned on
// odd rows: pitch 2047 floats).

#define ROW_W 4096
#define OUT_W 2047

__device__ __forceinline__ float pool4(float w0, float w1, float w2, float w3) {
    int mi = 0; float m = w0;
    if (w1 > m) { m = w1; mi = 1; }
    if (w2 > m) { m = w2; mi = 2; }
    if (w3 > m) { m = w3; mi = 3; }
    const float lo = (mi == 1) ? w0 : w1;
    const float hi = (mi == 1) ? w2 : w3;
    const float interior = 0.25f * lo + 0.5f * m + 0.25f * hi;
    return (mi == 0 || mi == 3) ? m : interior;
}

__global__ __launch_bounds__(256) void npool_kernel(const float* __restrict__ x,
                                                    float* __restrict__ out) {
    const int tid  = threadIdx.x;
    const int lane = tid & 63;
    const int wave = tid >> 6;
    const int row  = blockIdx.x;
    const float* rx = x + (size_t)row * ROW_W;
    float*       ro = out + (size_t)row * OUT_W;

    const int s0 = 4 * wave;            // this wave's first segment (of 16/row)

    // Phase 1: all loads up front (4 dense float4s/thread in flight).
    float4 v[4];
    #pragma unroll
    for (int t = 0; t < 4; ++t)
        v[t] = *reinterpret_cast<const float4*>(rx + 256 * (s0 + t) + 4 * lane);

    float2 e[4];
    if (lane == 63) {
        #pragma unroll
        for (int t = 0; t < 4; ++t) {
            int eb = 256 * (s0 + t) + 256;
            if (eb > ROW_W - 2) eb = ROW_W - 2;   // clamp: only segment 15 (value unused)
            e[t] = *reinterpret_cast<const float2*>(rx + eb);
        }
    }

    // Phase 2: share, compute, store.
    #pragma unroll
    for (int t = 0; t < 4; ++t) {
        float n0 = __shfl_down(v[t].x, 1, 64);
        float n1 = __shfl_down(v[t].y, 1, 64);
        if (lane == 63) { n0 = e[t].x; n1 = e[t].y; }

        const float r0 = pool4(v[t].x, v[t].y, v[t].z, v[t].w);   // o = 128s+2i
        const float r1 = pool4(v[t].z, v[t].w, n0, n1);           // o = 128s+2i+1

        const int o = 128 * (s0 + t) + 2 * lane;
        ro[o] = r0;
        if (o + 1 < OUT_W) ro[o + 1] = r1;    // masked only at s=15, lane=63
    }
}

extern "C" void kernel_launch(void* const* d_in, const int* in_sizes, int n_in,
                              void* d_out, int out_size, void* d_ws, size_t ws_size,
                              hipStream_t stream) {
    const float* x = (const float*)d_in[0];
    float* out = (float*)d_out;

    const int rows = in_sizes[0] / ROW_W;   // 8*32*64 = 16384
    npool_kernel<<<rows, 256, 0, stream>>>(x, out);
}